// Round 8
// baseline (175.592 us; speedup 1.0000x reference)
//
#include <hip/hip_runtime.h>
#include <math.h>
#include <stdint.h>

// Problem dims
#define NB  8
#define NC  256
#define NHW 4096   // H*W
#define NK  512

// d_out float offsets (outputs concatenated in return order)
#define OFF_SEL 0ULL
#define OFF_CW  8388608ULL              // NB*NC*NHW
#define OFF_KLD 8421376ULL              // + NB*NHW
#define OFF_MAT 8421377ULL              // + 1

// ws layout: double sw[512]; double kld_accum;  (4104 bytes)

__global__ void gumbel_prep(const float* __restrict__ cb, double* __restrict__ ws) {
    const int l = threadIdx.x & 63;
    const int w = threadIdx.x >> 6;
    const int k = blockIdx.x * 4 + w;           // grid 128 x 256 threads -> k in [0,512)
    const float4 v = *reinterpret_cast<const float4*>(cb + (size_t)k * NC + l * 4);
    double s = (double)v.x + (double)v.y + (double)v.z + (double)v.w;
    #pragma unroll
    for (int off = 32; off > 0; off >>= 1) s += __shfl_xor(s, off);
    if (l == 0) ws[k] = s;
    if (blockIdx.x == 0 && threadIdx.x == 0) ws[NK] = 0.0;   // zero kld accumulator
}

// One token per 8-lane octet. 512 threads = 64 tokens/block, grid 512.
// Per lane: 64 k's (k = 4*o + 32*j + q), 4 independent chains (q), 3-step octet merges.
// LDS 44,800 B -> 2-3 blocks/CU.
__global__ void __launch_bounds__(512, 4)
gumbel_main(const float* __restrict__ feats, const float* __restrict__ gumbel,
            const float* __restrict__ cb, double* __restrict__ ws,
            float* __restrict__ out) {
    __shared__ uint32_t p4_tile[128 * 64];  // 32768 B: dword (4 k's) x token, XOR-swizzled
    __shared__ float  sw_f[NK];             // 2048
    __shared__ double sf_d[64];             // 512
    __shared__ float  sf_f[64];             // 256
    __shared__ float  invS[64];             // 256
    __shared__ int    kcnt[64];             // 256
    __shared__ int    klist[64][17];        // 4352 (pad 17: 2-way banks in Phase D)
    __shared__ float  wlist[64][17];        // 4352

    const int tid = threadIdx.x;
    const int b   = blockIdx.x >> 6;   // 64 blocks per batch
    const int n0  = (blockIdx.x & 63) * 64;

    // ---- Phase A: sf[tok] = sum_c feats[b,c,n0+tok] in f64 (f32 copy for fast path) ----
    {
        double* part = reinterpret_cast<double*>(p4_tile);   // [8][64] alias, pre-pass only
        const int l = tid & 63, w = tid >> 6;
        const float* fp = feats + ((size_t)b * NC + w * 32) * NHW + n0 + l;
        double s = 0.0;
        #pragma unroll
        for (int i = 0; i < 32; ++i) s += (double)fp[(size_t)i * NHW];
        part[w * 64 + l] = s;
        sw_f[tid] = (float)ws[tid];
        __syncthreads();
        if (tid < 64) {
            double acc = 0.0;
            #pragma unroll
            for (int i = 0; i < 8; ++i) acc += part[i * 64 + tid];
            sf_d[tid] = acc; sf_f[tid] = (float)acc;
            kcnt[tid] = 0;
        }
        __syncthreads();
    }

    const int l   = tid & 63;
    const int wv  = tid >> 6;          // wave 0..7
    const int o   = l & 7;             // octet lane 0..7
    const int tok = wv * 8 + (l >> 3); // this lane's token 0..63
    const int n   = n0 + tok;
    const float sft = sf_f[tok];
    const float4* grow = reinterpret_cast<const float4*>(gumbel + ((size_t)(b * NHW) + n) * NK);

    // ---- Pass 1: top-2 / argmax / E / T1, 4 chains per lane, no LDS in loop ----
    float m[4], ys[4], Ea[4], T1[4]; int kb[4];
    #pragma unroll
    for (int q = 0; q < 4; ++q) { m[q] = -1e30f; ys[q] = -1e30f; Ea[q] = 0.f; T1[q] = 0.f; kb[q] = 0; }
    #pragma unroll
    for (int j = 0; j < 16; ++j) {
        const float4 g4  = grow[o + 8 * j];
        const float4 sw4 = *reinterpret_cast<const float4*>(&sw_f[4 * o + 32 * j]);
        const float gs[4] = {g4.x, g4.y, g4.z, g4.w};
        const float ss[4] = {sw4.x, sw4.y, sw4.z, sw4.w};
        #pragma unroll
        for (int q = 0; q < 4; ++q) {
            const int k = 4 * o + 32 * j + q;
            const float d = sft - ss[q];
            const float logit = __expf(-d * d);
            const float y = logit + gs[q];
            if (y > m[q]) { ys[q] = m[q]; m[q] = y; kb[q] = k; }   // k ascending in j -> lowest-k ties
            else ys[q] = fmaxf(ys[q], y);
            // el = exp(logit) via (e^x-1)/x poly: err(E) ~1e-5 rel, invisible in kld
            const float h = fmaf(logit, fmaf(logit, fmaf(logit, fmaf(logit,
                              1.f/120.f, 1.f/24.f), 1.f/6.f), 0.5f), 1.f);
            const float xh = logit * h;
            Ea[q] += xh;
            T1[q] = fmaf(logit, 1.f + xh, T1[q]);
        }
    }
    // merge 4 chains (ascending q keeps lowest k)
    float M = m[0], YS = ys[0]; int KB = kb[0];
    #pragma unroll
    for (int q = 1; q < 4; ++q) {
        const float nys = fmaxf(fmaxf(YS, ys[q]), fminf(M, m[q]));
        if (m[q] > M || (m[q] == M && kb[q] < KB)) { M = m[q]; KB = kb[q]; }
        YS = nys;
    }
    float E = Ea[0] + Ea[1] + Ea[2] + Ea[3];
    float T = T1[0] + T1[1] + T1[2] + T1[3];
    // octet merge: 3 shuffle steps only
    #pragma unroll
    for (int off = 1; off < 8; off <<= 1) {
        const float oM = __shfl_xor(M, off);
        const int   oK = __shfl_xor(KB, off);
        const float oY = __shfl_xor(YS, off);
        const float oE = __shfl_xor(E, off);
        const float oT = __shfl_xor(T, off);
        const float nys = fmaxf(fmaxf(YS, oY), fminf(M, oM));
        if (oM > M || (oM == M && oK < KB)) { M = oM; KB = oK; }
        YS = nys; E += oE; T += oT;
    }
    E += 512.f;

    // rare exact f64 path (octet-uniform branch); f32-path y err <= ~1.3e-4 << 5e-3 gap
    if (M - YS < 5e-3f) {
        const double sfd = sf_d[tok];
        const float* gsc = gumbel + ((size_t)(b * NHW) + n) * NK;
        double ym64 = -1.0e300; int kb64 = 0;
        for (int j = 0; j < 16; ++j)
            #pragma unroll
            for (int q = 0; q < 4; ++q) {
                const int k = 4 * o + 32 * j + q;
                const double dd = sfd - ws[k];
                const double aff = dd * dd;
                const double lg = (aff < 45.0) ? exp(-aff) : 0.0;   // <3e-20 invisible
                const double yy = lg + (double)gsc[k];
                if (yy > ym64) { ym64 = yy; kb64 = k; }
            }
        #pragma unroll
        for (int off = 1; off < 8; off <<= 1) {
            const double oy = __shfl_xor(ym64, off);
            const int    ok = __shfl_xor(kb64, off);
            if (oy > ym64 || (oy == ym64 && ok < kb64)) { ym64 = oy; kb64 = ok; }
        }
        KB = kb64;
    }
    if (o == 0) out[OFF_CW + (size_t)b * NHW + n] = (float)KB;

    // kld: wave-sum of per-token values (one per octet leader), f64, one atomic per wave
    {
        double kd = (o == 0) ? (double)(T / E + 6.2383246250395075f - logf(E)) : 0.0;
        #pragma unroll
        for (int off = 1; off < 64; off <<= 1) kd += __shfl_xor(kd, off);
        if (l == 0) atomicAdd(&ws[NK], kd);
    }

    // ---- Pass 2: p = exp((y-M)*100) (unnormalized), u8 store + S + top-k list ----
    const float nM100 = -100.f * M;
    float s4[4] = {0.f, 0.f, 0.f, 0.f};
    #pragma unroll
    for (int j = 0; j < 16; ++j) {
        const float4 g4  = grow[o + 8 * j];                       // L2-hit re-read
        const float4 sw4 = *reinterpret_cast<const float4*>(&sw_f[4 * o + 32 * j]);
        const float gs[4] = {g4.x, g4.y, g4.z, g4.w};
        const float ss[4] = {sw4.x, sw4.y, sw4.z, sw4.w};
        uint32_t pack = 0;
        #pragma unroll
        for (int q = 0; q < 4; ++q) {
            const int k = 4 * o + 32 * j + q;
            const float d = sft - ss[q];
            const float logit = __expf(-d * d);
            const float y = logit + gs[q];
            const float p = __expf(fmaf(100.f, y, nM100));        // in (0,1]
            s4[q] += p;
            pack |= ((uint32_t)fmaf(p, 255.f, 0.5f)) << (8 * q);
            if (p > 1e-7f) {                                      // superset of w>1e-7 (S>=1)
                const int id2 = atomicAdd(&kcnt[tok], 1);
                if (id2 < 16) { klist[tok][id2] = k; wlist[tok][id2] = p; }
            }
        }
        const int k4 = o + 8 * j;                                 // k4 & 7 == o
        p4_tile[k4 * 64 + (tok ^ (o << 3))] = pack;               // XOR swizzle: 2-way banks
    }
    float S = s4[0] + s4[1] + s4[2] + s4[3];
    #pragma unroll
    for (int off = 1; off < 8; off <<= 1) S += __shfl_xor(S, off);
    if (o == 0) invS[tok] = 1.f / S;
    __syncthreads();

    // ---- Phase C: mat_id_probs (B,K,N); wave wv owns k rows wv*64..+63; 256B NT runs ----
    {
        const float f = invS[l] * (1.f / 255.f);                  // lane l = token l
        float* obase = out + OFF_MAT + ((size_t)b * NK + wv * 64) * NHW + n0 + l;
        #pragma unroll
        for (int p4i = 0; p4i < 16; ++p4i) {
            const int k4 = 16 * wv + p4i;
            const uint32_t pk = p4_tile[k4 * 64 + (l ^ ((k4 & 7) << 3))];
            #pragma unroll
            for (int q = 0; q < 4; ++q) {
                const float v = (float)((pk >> (8 * q)) & 255u) * f;
                __builtin_nontemporal_store(v, obase + (size_t)(p4i * 4 + q) * NHW);
            }
        }
    }

    // ---- Phase D: sel_codewords (B,C,N) from sparse top-k list (NT stores) ----
    {
        const int cnt = min(kcnt[l], 16);
        const float inv = invS[l];
        #pragma unroll
        for (int half = 0; half < 2; ++half) {
            float acc[16];
            #pragma unroll
            for (int i2 = 0; i2 < 16; ++i2) acc[i2] = 0.f;
            for (int e = 0; e < cnt; ++e) {
                const int k = klist[l][e];
                const float wgt = wlist[l][e] * inv;
                const float4* cr = reinterpret_cast<const float4*>(
                    cb + (size_t)k * NC + wv * 32 + half * 16);
                #pragma unroll
                for (int q = 0; q < 4; ++q) {
                    const float4 v = cr[q];
                    acc[q * 4 + 0] += wgt * v.x; acc[q * 4 + 1] += wgt * v.y;
                    acc[q * 4 + 2] += wgt * v.z; acc[q * 4 + 3] += wgt * v.w;
                }
            }
            float* basep = out + OFF_SEL + ((size_t)b * NC + wv * 32 + half * 16) * NHW + n0 + l;
            #pragma unroll
            for (int i2 = 0; i2 < 16; ++i2)
                __builtin_nontemporal_store(acc[i2], basep + (size_t)i2 * NHW);
        }
    }
}

__global__ void gumbel_fin(const double* __restrict__ ws, float* __restrict__ out) {
    out[OFF_KLD] = (float)(ws[NK] * (1.0 / 32768.0));
}

extern "C" void kernel_launch(void* const* d_in, const int* in_sizes, int n_in,
                              void* d_out, int out_size, void* d_ws, size_t ws_size,
                              hipStream_t stream) {
    const float* feats = (const float*)d_in[0];
    const float* cb    = (const float*)d_in[1];
    const float* gum   = (const float*)d_in[2];
    double* ws = (double*)d_ws;
    float* out = (float*)d_out;
    gumbel_prep<<<128, 256, 0, stream>>>(cb, ws);
    gumbel_main<<<512, 512, 0, stream>>>(feats, gum, cb, ws, out);
    gumbel_fin<<<1, 1, 0, stream>>>(ws, out);
}

// Round 9
// 115.101 us; speedup vs baseline: 1.5256x; 1.5256x over previous
//
#include <hip/hip_runtime.h>
#include <math.h>
#include <stdint.h>

// Problem dims
#define NB  8
#define NC  256
#define NHW 4096   // H*W
#define NK  512

// d_out float offsets (outputs concatenated in return order)
#define OFF_SEL 0ULL
#define OFF_CW  8388608ULL              // NB*NC*NHW
#define OFF_KLD 8421376ULL              // + NB*NHW
#define OFF_MAT 8421377ULL              // + 1
#define MAT_COUNT 16777216ULL           // NB*NK*NHW
#define OUT_TOTAL (OFF_MAT + MAT_COUNT) // 25198593

typedef float f4v __attribute__((ext_vector_type(4)));

// ws layout: double sw[512]; double kld_accum;  (4104 bytes)

__global__ void gumbel_prep(const float* __restrict__ cb, double* __restrict__ ws) {
    const int l = threadIdx.x & 63;
    const int w = threadIdx.x >> 6;
    const int k = blockIdx.x * 4 + w;           // grid 128 x 256 threads -> k in [0,512)
    const float4 v = *reinterpret_cast<const float4*>(cb + (size_t)k * NC + l * 4);
    double s = (double)v.x + (double)v.y + (double)v.z + (double)v.w;
    #pragma unroll
    for (int off = 32; off > 0; off >>= 1) s += __shfl_xor(s, off);
    if (l == 0) ws[k] = s;
    if (blockIdx.x == 0 && threadIdx.x == 0) ws[NK] = 0.0;   // zero kld accumulator
}

// Zero-fill mat_id_probs region: contiguous NT float4 stream (aligned body + scalar edges)
__global__ void zmat(float* __restrict__ out) {
    const size_t base4 = 2105345ULL;            // 8421380/4 : first 16B-aligned float4
    const size_t n4    = 4194303ULL;            // float4 count, tail float handled below
    size_t i = (size_t)blockIdx.x * blockDim.x + threadIdx.x;
    const size_t stride = (size_t)gridDim.x * blockDim.x;
    f4v* o4 = reinterpret_cast<f4v*>(out) + base4;
    const f4v z = {0.f, 0.f, 0.f, 0.f};
    for (; i < n4; i += stride) __builtin_nontemporal_store(z, o4 + i);
    if (blockIdx.x == 0 && threadIdx.x < 4) {
        out[OFF_MAT + threadIdx.x] = 0.f;       // head floats 8421377..80
        if (threadIdx.x == 0) out[OUT_TOTAL - 1] = 0.f;  // tail float
    }
}

// One token per 8-lane octet; ONE pass over gumbel (online softmax, seeded max);
// sparse candidate list in LDS; mat written by sparse scatter onto zero-filled bg.
// 512 threads = 64 tokens/block, grid 512. LDS ~37 KB.
__global__ void __launch_bounds__(512)
gs_main(const float* __restrict__ feats, const float* __restrict__ gumbel,
        const float* __restrict__ cb, double* __restrict__ ws,
        float* __restrict__ out) {
    __shared__ float  ylist[64 * 57];       // candidate y (pad 57)
    __shared__ int    klst [64 * 57];       // candidate k
    __shared__ float  sw_f[NK];
    __shared__ double sf_d[64];
    __shared__ float  sf_f[64];
    __shared__ int    icnt[64];             // raw insert count
    __shared__ int    kcnt[64];             // final candidate count (<=9)
    __shared__ int    fk[64][9];            // final k   (pad 9 -> 2-way banks in D)
    __shared__ float  fw[64][9];            // final w

    const int tid = threadIdx.x;
    const int b   = blockIdx.x >> 6;
    const int n0  = (blockIdx.x & 63) * 64;

    // ---- Phase A: sf = channel sum of feats (f64), sw -> LDS f32 ----
    {
        double* part = reinterpret_cast<double*>(ylist);   // [8][64] alias, pre-barrier
        const int l = tid & 63, w = tid >> 6;
        const float* fp = feats + ((size_t)b * NC + w * 32) * NHW + n0 + l;
        double s = 0.0;
        #pragma unroll
        for (int i = 0; i < 32; ++i) s += (double)fp[(size_t)i * NHW];
        part[w * 64 + l] = s;
        sw_f[tid] = (float)ws[tid];
        __syncthreads();
        if (tid < 64) {
            double a = 0.0;
            #pragma unroll
            for (int i = 0; i < 8; ++i) a += part[i * 64 + tid];
            sf_d[tid] = a; sf_f[tid] = (float)a;
            icnt[tid] = 0; kcnt[tid] = 0;
        }
        __syncthreads();
    }

    const int l   = tid & 63;
    const int wv  = tid >> 6;
    const int o   = l & 7;                 // octet lane
    const int tok = wv * 8 + (l >> 3);     // token 0..63
    const int n   = n0 + tok;
    const float sft = sf_f[tok];
    const float4* grow = reinterpret_cast<const float4*>(gumbel + ((size_t)(b * NHW) + n) * NK);

    // ---- Single pass: online (m,s), top-2, argmax, E, T, candidate inserts ----
    // m seeded 2.0: P(token max < 2) = exp(-512*e^-2) ~ e^-69 (softmax shift-invariant,
    // seed only gates inserts). k = 4*o + 32*j + q, ascending per lane for tie-break.
    float m = 2.0f, ys = -1.0e30f, s = 0.f, E = 0.f, T = 0.f;
    int kb = 0;
    #pragma unroll 4
    for (int j = 0; j < 16; ++j) {
        const float4 g4  = grow[o + 8 * j];
        const float4 sw4 = *reinterpret_cast<const float4*>(&sw_f[4 * o + 32 * j]);
        const float gs[4] = {g4.x, g4.y, g4.z, g4.w};
        const float ss[4] = {sw4.x, sw4.y, sw4.z, sw4.w};
        #pragma unroll
        for (int q = 0; q < 4; ++q) {
            const int k = 4 * o + 32 * j + q;
            const float d = sft - ss[q];
            const float logit = __expf(-d * d);
            const float y = logit + gs[q];
            // E,T poly: e^logit - 1 = logit*h, logit in (0,1]
            const float h = fmaf(logit, fmaf(logit, fmaf(logit, fmaf(logit,
                              1.f/120.f, 1.f/24.f), 1.f/6.f), 0.5f), 1.f);
            const float xh = logit * h;
            E += xh;
            T = fmaf(logit, 1.f + xh, T);
            // online max + sum (one exp): strict > keeps lowest k
            const bool gt = y > m;
            const float e = __expf((gt ? m - y : y - m) * 100.0f);
            s = gt ? fmaf(s, e, 1.f) : (s + e);
            ys = gt ? m : fmaxf(ys, y);
            if (gt) { m = y; kb = k; }
            if (y > m - 0.17f) {            // candidate (always true for new max)
                const int idx = atomicAdd(&icnt[tok], 1);
                if (idx < 56) { ylist[tok * 57 + idx] = y; klst[tok * 57 + idx] = k; }
            }
        }
    }
    // octet merge: 3 shuffle steps
    #pragma unroll
    for (int off = 1; off < 8; off <<= 1) {
        const float om  = __shfl_xor(m, off);
        const int   okb = __shfl_xor(kb, off);
        const float oys = __shfl_xor(ys, off);
        const float os  = __shfl_xor(s, off);
        const float oE  = __shfl_xor(E, off);
        const float oT  = __shfl_xor(T, off);
        const float nm  = fmaxf(m, om);
        s = s * __expf((m - nm) * 100.f) + os * __expf((om - nm) * 100.f);
        const float nys = fmaxf(fmaxf(ys, oys), fminf(m, om));
        if (om > m || (om == m && okb < kb)) kb = okb;
        m = nm; ys = nys; E += oE; T += oT;
    }
    E += 512.f;

    // rare exact f64 argmax (octet-uniform); f32 y err ~1.3e-4 << 5e-3 gap
    if (m - ys < 5e-3f) {
        const double sfd = sf_d[tok];
        const float* gsc = gumbel + ((size_t)(b * NHW) + n) * NK;
        double ym64 = -1.0e300; int kb64 = 0;
        for (int j = 0; j < 16; ++j)
            #pragma unroll
            for (int q = 0; q < 4; ++q) {
                const int k = 4 * o + 32 * j + q;
                const double dd = sfd - ws[k];
                const double aff = dd * dd;
                const double lg = (aff < 45.0) ? exp(-aff) : 0.0;   // <3e-20 invisible
                const double yy = lg + (double)gsc[k];
                if (yy > ym64) { ym64 = yy; kb64 = k; }
            }
        #pragma unroll
        for (int off = 1; off < 8; off <<= 1) {
            const double oy = __shfl_xor(ym64, off);
            const int    ok = __shfl_xor(kb64, off);
            if (oy > ym64 || (oy == ym64 && ok < kb64)) { ym64 = oy; kb64 = ok; }
        }
        kb = kb64;
    }
    if (o == 0) out[OFF_CW + (size_t)b * NHW + n] = (float)kb;

    // kld: per-token T/E + ln512 - lnE (eps negligible), wave-reduce, 1 atomic/wave
    {
        double kd = (o == 0) ? (double)(T / E + 6.2383246250395075 - (double)logf(E)) : 0.0;
        #pragma unroll
        for (int off = 1; off < 64; off <<= 1) kd += __shfl_xor(kd, off);
        if (l == 0) atomicAdd(&ws[NK], kd);
    }

    // ---- Filter/compact candidates + sparse mat scatter (octet leader) ----
    if (o == 0) {
        const int cnt = min(icnt[tok], 56);
        const float inv = 1.f / s;
        const float thr = m - 0.17f;        // w >= ~4e-8 below threshold -> stays 0
        float* orow = out + OFF_MAT + ((size_t)b * NK) * NHW + n;
        int c2 = 0;
        for (int e = 0; e < cnt; ++e) {
            const float yy = ylist[tok * 57 + e];
            if (yy > thr) {
                const float wgt = __expf((yy - m) * 100.f) * inv;
                const int k = klst[tok * 57 + e];
                if (c2 < 9) { fk[tok][c2] = k; fw[tok][c2] = wgt; }
                ++c2;
                orow[(size_t)k * NHW] = wgt;                  // sparse scatter (zmat bg)
            }
        }
        kcnt[tok] = min(c2, 9);
    }
    __syncthreads();

    // ---- Phase D: sel_codewords (B,C,N) from sparse list (NT stores, 256B runs) ----
    {
        const int cnt = kcnt[l];            // lane l = token l
        #pragma unroll
        for (int half = 0; half < 2; ++half) {
            float acc[16];
            #pragma unroll
            for (int i2 = 0; i2 < 16; ++i2) acc[i2] = 0.f;
            for (int e = 0; e < cnt; ++e) {
                const int k = fk[l][e];
                const float wgt = fw[l][e];
                const float4* cr = reinterpret_cast<const float4*>(
                    cb + (size_t)k * NC + wv * 32 + half * 16);
                #pragma unroll
                for (int q = 0; q < 4; ++q) {
                    const float4 v = cr[q];
                    acc[q * 4 + 0] += wgt * v.x; acc[q * 4 + 1] += wgt * v.y;
                    acc[q * 4 + 2] += wgt * v.z; acc[q * 4 + 3] += wgt * v.w;
                }
            }
            float* basep = out + OFF_SEL + ((size_t)b * NC + wv * 32 + half * 16) * NHW + n0 + l;
            #pragma unroll
            for (int i2 = 0; i2 < 16; ++i2)
                __builtin_nontemporal_store(acc[i2], basep + (size_t)i2 * NHW);
        }
    }
}

__global__ void gumbel_fin(const double* __restrict__ ws, float* __restrict__ out) {
    out[OFF_KLD] = (float)(ws[NK] * (1.0 / 32768.0));
}

extern "C" void kernel_launch(void* const* d_in, const int* in_sizes, int n_in,
                              void* d_out, int out_size, void* d_ws, size_t ws_size,
                              hipStream_t stream) {
    const float* feats = (const float*)d_in[0];
    const float* cb    = (const float*)d_in[1];
    const float* gum   = (const float*)d_in[2];
    double* ws = (double*)d_ws;
    float* out = (float*)d_out;
    gumbel_prep<<<128, 256, 0, stream>>>(cb, ws);
    zmat<<<2048, 256, 0, stream>>>(out);
    gs_main<<<512, 512, 0, stream>>>(feats, gum, cb, ws, out);
    gumbel_fin<<<1, 1, 0, stream>>>(ws, out);
}

// Round 10
// 67.364 us; speedup vs baseline: 2.6066x; 1.7086x over previous
//
#include <hip/hip_runtime.h>
#include <math.h>
#include <stdint.h>

// Problem dims
#define NB  8
#define NC  256
#define NHW 4096   // H*W
#define NK  512

// d_out float offsets (outputs concatenated in return order)
#define OFF_SEL 0ULL
#define OFF_CW  8388608ULL              // NB*NC*NHW
#define OFF_KLD 8421376ULL              // + NB*NHW
#define OFF_MAT 8421377ULL              // + 1
#define MAT_COUNT 16777216ULL           // NB*NK*NHW
#define OUT_TOTAL (OFF_MAT + MAT_COUNT) // 25198593

typedef float f4v __attribute__((ext_vector_type(4)));

// ws layout: double sw[512]; double kld_accum;  (4104 bytes)

__global__ void gumbel_prep(const float* __restrict__ cb, double* __restrict__ ws) {
    const int l = threadIdx.x & 63;
    const int w = threadIdx.x >> 6;
    const int k = blockIdx.x * 4 + w;           // grid 128 x 256 threads -> k in [0,512)
    const float4 v = *reinterpret_cast<const float4*>(cb + (size_t)k * NC + l * 4);
    double s = (double)v.x + (double)v.y + (double)v.z + (double)v.w;
    #pragma unroll
    for (int off = 32; off > 0; off >>= 1) s += __shfl_xor(s, off);
    if (l == 0) ws[k] = s;
    if (blockIdx.x == 0 && threadIdx.x == 0) ws[NK] = 0.0;   // zero kld accumulator
}

// Zero-fill mat_id_probs region: contiguous NT float4 stream (aligned body + scalar edges)
__global__ void zmat(float* __restrict__ out) {
    const size_t base4 = 2105345ULL;            // 8421380/4 : first 16B-aligned float4
    const size_t n4    = 4194303ULL;            // float4 count, tail float handled below
    size_t i = (size_t)blockIdx.x * blockDim.x + threadIdx.x;
    const size_t stride = (size_t)gridDim.x * blockDim.x;
    f4v* o4 = reinterpret_cast<f4v*>(out) + base4;
    const f4v z = {0.f, 0.f, 0.f, 0.f};
    for (; i < n4; i += stride) __builtin_nontemporal_store(z, o4 + i);
    if (blockIdx.x == 0 && threadIdx.x < 4) {
        out[OFF_MAT + threadIdx.x] = 0.f;       // head floats 8421377..80
        if (threadIdx.x == 0) out[OUT_TOTAL - 1] = 0.f;  // tail float
    }
}

// Wave-per-token (r7 skeleton) + sparse mat scatter. 512 threads = 8 waves,
// wave w handles tokens w*8..w*8+7. k = l + 64*jj: sw hoisted to registers,
// hot loop has NO LDS ops, NO atomics, NO branches. LDS ~16 KB.
__global__ void __launch_bounds__(512, 4)
gs_main(const float* __restrict__ feats, const float* __restrict__ gumbel,
        const float* __restrict__ cb, double* __restrict__ ws,
        float* __restrict__ out) {
    __shared__ double part[8][64];          // 4096
    __shared__ float  sw_f[NK];             // 2048
    __shared__ double sf_d[64];             // 512
    __shared__ float  sf_f[64];             // 256
    __shared__ int    kcnt[64];             // 256
    __shared__ int    klist[64][17];        // 4352 (17: conflict-free rows)
    __shared__ float  wlist[64][17];        // 4352
    __shared__ double kldp[8];              // 64

    const int tid = threadIdx.x;
    const int l   = tid & 63;          // lane
    const int w   = tid >> 6;          // wave 0..7
    const int b   = blockIdx.x >> 6;   // 64 blocks per batch
    const int n0  = (blockIdx.x & 63) * 64;

    // ---- Phase A: sf[tok] = sum_c feats[b,c,n0+tok] (f64); sw -> LDS f32 ----
    {
        const float* fp = feats + ((size_t)b * NC + w * 32) * NHW + n0 + l;
        double s = 0.0;
        #pragma unroll
        for (int i = 0; i < 32; ++i) s += (double)fp[(size_t)i * NHW];
        part[w][l] = s;
        sw_f[tid] = (float)ws[tid];
        __syncthreads();
        if (tid < 64) {
            double a = 0.0;
            #pragma unroll
            for (int i = 0; i < 8; ++i) a += part[i][tid];
            sf_d[tid] = a; sf_f[tid] = (float)a;
            kcnt[tid] = 0;
        }
        __syncthreads();
    }

    // hoist this lane's 8 sw values into registers (same for all its tokens)
    float swreg[8];
    #pragma unroll
    for (int jj = 0; jj < 8; ++jj) swreg[jj] = sw_f[l + 64 * jj];

    // ---- Phase B: 8 tokens per wave; k = l + 64*jj (scalar coalesced g loads) ----
    double kld_wave = 0.0;
    float gc[8], gn[8];
    {
        const float* gp = gumbel + ((size_t)(b * NHW) + n0 + w * 8) * NK;
        #pragma unroll
        for (int jj = 0; jj < 8; ++jj) gc[jj] = gp[l + 64 * jj];
    }
    #pragma unroll
    for (int i = 0; i < 8; ++i) {
        const int tt = w * 8 + i;
        const int n  = n0 + tt;
        if (i < 7) {                        // prefetch next token's row
            const float* gpn = gumbel + ((size_t)(b * NHW) + n + 1) * NK;
            #pragma unroll
            for (int jj = 0; jj < 8; ++jj) gn[jj] = gpn[l + 64 * jj];
        }
        const float sft = sf_f[tt];
        float y[8];
        float M = -1.0e30f, YS = -1.0e30f; int KB = 0;
        float E = 0.f, T = 0.f;
        #pragma unroll
        for (int jj = 0; jj < 8; ++jj) {    // hot loop: pure VALU, k ascending
            const int k = l + 64 * jj;
            const float d = sft - swreg[jj];
            const float logit = __expf(-d * d);
            const float yy = logit + gc[jj];
            y[jj] = yy;
            // e^logit - 1 = logit*h (5th order, rel err <2e-3 abs on E~513: ok)
            const float h = fmaf(logit, fmaf(logit, fmaf(logit, fmaf(logit,
                              1.f/120.f, 1.f/24.f), 1.f/6.f), 0.5f), 1.f);
            const float xh = logit * h;
            E += xh;
            T = fmaf(logit, 1.f + xh, T);
            if (yy > M) { YS = M; M = yy; KB = k; }      // strict >: lowest k on ties
            else YS = fmaxf(YS, yy);
        }
        // merged butterfly: argmax + 2nd max + E + T (6 steps, no exps)
        #pragma unroll
        for (int off = 32; off > 0; off >>= 1) {
            const float oM = __shfl_xor(M, off);
            const int   oK = __shfl_xor(KB, off);
            const float oY = __shfl_xor(YS, off);
            const float oE = __shfl_xor(E, off);
            const float oT = __shfl_xor(T, off);
            const float nys = fmaxf(fmaxf(YS, oY), fminf(M, oM));
            if (oM > M || (oM == M && oK < KB)) { M = oM; KB = oK; }
            YS = nys; E += oE; T += oT;
        }
        E += 512.f;

        // rare exact f64 argmax (wave-uniform); f32 y err ~1e-5 << 5e-3 gap
        if (M - YS < 5e-3f) {
            const double sfd = sf_d[tt];
            double ym64 = -1.0e300; int kb64 = 0;
            #pragma unroll
            for (int jj = 0; jj < 8; ++jj) {
                const int k = l + 64 * jj;
                const double dd = sfd - ws[k];
                const double aff = dd * dd;
                const double lg = (aff < 45.0) ? exp(-aff) : 0.0;   // <3e-20 invisible
                const double yy = lg + (double)gc[jj];
                if (yy > ym64) { ym64 = yy; kb64 = k; }
            }
            #pragma unroll
            for (int off = 32; off > 0; off >>= 1) {
                const double oy = __shfl_xor(ym64, off);
                const int    ok = __shfl_xor(kb64, off);
                if (oy > ym64 || (oy == ym64 && ok < kb64)) { ym64 = oy; kb64 = ok; }
            }
            KB = kb64;
        }
        if (l == 0) {
            out[OFF_CW + (size_t)b * NHW + n] = (float)KB;
            // kld_tok = T/E + ln512 - lnE (eps=1e-10 negligible)
            kld_wave += (double)(T / E + 6.2383246250395075f - logf(E));
        }

        // p numerators (8 exps, underflow->0); S over candidates only (err<2e-5 rel)
        float pr[8]; float Sl = 0.f;
        #pragma unroll
        for (int jj = 0; jj < 8; ++jj) {
            const float p = __expf((y[jj] - M) * 100.0f);
            pr[jj] = p; Sl += p;
        }
        #pragma unroll
        for (int off = 32; off > 0; off >>= 1) Sl += __shfl_xor(Sl, off);
        const float inv = 1.0f / Sl;

        // sparse outputs: ~1.3 candidates/token (p>4e-8 <=> w in the 1e-7 window)
        #pragma unroll
        for (int jj = 0; jj < 8; ++jj) {
            if (pr[jj] > 4e-8f) {
                const int k = l + 64 * jj;
                const float wgt = pr[jj] * inv;
                out[OFF_MAT + ((size_t)b * NK + k) * NHW + n] = wgt;   // zmat bg
                const int idx = atomicAdd(&kcnt[tt], 1);
                if (idx < 16) { klist[tt][idx] = k; wlist[tt][idx] = wgt; }
            }
        }
        #pragma unroll
        for (int jj = 0; jj < 8; ++jj) gc[jj] = gn[jj];
    }
    if (l == 0) kldp[w] = kld_wave;
    __syncthreads();
    if (tid == 0) {
        double acc = 0.0;
        #pragma unroll
        for (int i = 0; i < 8; ++i) acc += kldp[i];
        atomicAdd(&ws[NK], acc);            // one global atomic per block (512 total)
    }

    // ---- Phase D: sel_codewords (B,C,N) from sparse list (NT stores, 256B runs) ----
    {
        const int cnt = min(kcnt[l], 16);   // lane l = token l
        #pragma unroll
        for (int half = 0; half < 2; ++half) {
            float acc[16];
            #pragma unroll
            for (int i2 = 0; i2 < 16; ++i2) acc[i2] = 0.f;
            for (int e = 0; e < cnt; ++e) {
                const int k = klist[l][e];
                const float wgt = wlist[l][e];
                const float4* cr = reinterpret_cast<const float4*>(
                    cb + (size_t)k * NC + w * 32 + half * 16);
                #pragma unroll
                for (int q = 0; q < 4; ++q) {
                    const float4 v = cr[q];
                    acc[q * 4 + 0] += wgt * v.x; acc[q * 4 + 1] += wgt * v.y;
                    acc[q * 4 + 2] += wgt * v.z; acc[q * 4 + 3] += wgt * v.w;
                }
            }
            float* basep = out + OFF_SEL + ((size_t)b * NC + w * 32 + half * 16) * NHW + n0 + l;
            #pragma unroll
            for (int i2 = 0; i2 < 16; ++i2)
                __builtin_nontemporal_store(acc[i2], basep + (size_t)i2 * NHW);
        }
    }
}

__global__ void gumbel_fin(const double* __restrict__ ws, float* __restrict__ out) {
    out[OFF_KLD] = (float)(ws[NK] * (1.0 / 32768.0));
}

extern "C" void kernel_launch(void* const* d_in, const int* in_sizes, int n_in,
                              void* d_out, int out_size, void* d_ws, size_t ws_size,
                              hipStream_t stream) {
    const float* feats = (const float*)d_in[0];
    const float* cb    = (const float*)d_in[1];
    const float* gum   = (const float*)d_in[2];
    double* ws = (double*)d_ws;
    float* out = (float*)d_out;
    gumbel_prep<<<128, 256, 0, stream>>>(cb, ws);
    zmat<<<2048, 256, 0, stream>>>(out);
    gs_main<<<512, 512, 0, stream>>>(feats, gum, cb, ws, out);
    gumbel_fin<<<1, 1, 0, stream>>>(ws, out);
}